// Round 3
// baseline (93.253 us; speedup 1.0000x reference)
//
#include <hip/hip_runtime.h>

#define NPSI 256
#define MM 8
#define KK 4
#define NMP (MM / 2)

typedef float v2f __attribute__((ext_vector_type(2)));
typedef float v4f __attribute__((ext_vector_type(4)));

#if __has_builtin(__builtin_amdgcn_exp2f)
#define EXP2F(x) __builtin_amdgcn_exp2f(x)
#else
#define EXP2F(x) exp2f(x)
#endif
// hardware v_sin/v_cos take REVOLUTIONS (sin(2*pi*x)), valid |x|<=256
#define SIN_REV(x) __builtin_amdgcn_sinf(x)
#define COS_REV(x) __builtin_amdgcn_cosf(x)

#define VFMA(a,b,c) __builtin_elementwise_fma((v2f)(a),(v2f)(b),(v2f)(c))

// ---------------------------------------------------------------------------
// Prep: fold all per-mode constants + the cubic-Hermite q-table ONCE into
// d_ws. Mode table layout: [mp][pair 0..29][lane], pair p at mp*60 + 2p,
// lane = m&1:
//   pairs 0..5 : psi0*inv_ps, inv_ps, inv_as, nf, theta0, omega
//   pairs 6+6c : a0(=c0-2c3-2c5), c1, c3, c2, c4, 4*c5   for comp c=0..3
// Hermite q-coeffs at tb+256: [255][4] = {C0,C1,C2,C3}, q(s)=((C3 s+C2)s+C1)s+C0.
// Kills the 4-deep dependent scattered-load chain in the main prologue.
// ---------------------------------------------------------------------------
__global__ __launch_bounds__(256) void prep_kernel(
    const float* __restrict__ q_vals,
    const float* __restrict__ theta0_a,
    const float* __restrict__ omega_a,
    const float* __restrict__ psi0_a,
    const float* __restrict__ psi_scale_a,
    const float* __restrict__ alpha_scale_a,
    const float* __restrict__ gh_a,        // [M,4,6]
    const int*   __restrict__ n_a,
    float* __restrict__ tb)
{
    const int tid = threadIdx.x;
    if (tid < NPSI - 1) {
        const int i = tid;
        const float f0 = q_vals[i], f1 = q_vals[i + 1];
        const float d0 = (i == 0)        ? (f1 - f0) : 0.5f * (f1 - q_vals[i - 1]);
        const float d1 = (i == NPSI - 2) ? (f1 - f0) : 0.5f * (q_vals[i + 2] - f0);
        v4f c;
        c.x = f0;
        c.y = d0;
        c.z = 3.f * (f1 - f0) - 2.f * d0 - d1;
        c.w = 2.f * (f0 - f1) + d0 + d1;
        *(v4f*)(tb + 256 + 4 * i) = c;
    }
    if (tid < MM) {
        const int m = tid, mp = m >> 1, lane = m & 1;
        float* b = tb + mp * 60 + lane;
        const float invps = 1.0f / psi_scale_a[m];
        b[0]  = psi0_a[m] * invps;
        b[2]  = invps;
        b[4]  = 1.0f / alpha_scale_a[m];
        b[6]  = (float)n_a[m];
        b[8]  = theta0_a[m];
        b[10] = omega_a[m];
    }
    if (tid < MM * 4) {
        const int m = tid >> 2, comp = tid & 3;
        const int mp = m >> 1, lane = m & 1;
        const float* c = gh_a + m * 24 + comp * 6;
        float* b = tb + mp * 60 + (6 + comp * 6) * 2 + lane;
        b[0]  = fmaf(-2.f, c[3] + c[5], c[0]);  // a0 fold
        b[2]  = c[1];
        b[4]  = c[3];
        b[6]  = c[2];
        b[8]  = c[4];
        b[10] = 4.f * c[5];                     // pf4 prefold (4y^2 term)
    }
}

// One element per thread; v2f lanes hold the (m, m+1) mode pair.
// mp-loop unroll 2: two independent mp chains interleave, so one mp's exp
// cluster hides under the other's seed-trig/setup. (256,5): 102-VGPR budget,
// ~96 live with unroll 2, 5 waves/SIMD resident.
__global__ __launch_bounds__(256, 5) void eik_kernel(
    const float* __restrict__ t_ptr,
    const float* __restrict__ psi_a,
    const float* __restrict__ theta_a,
    const float* __restrict__ varphi_a,
    const float* __restrict__ tb,          // folded table (d_ws)
    float* __restrict__ out,               // [2*N]: phi then apar
    int N)
{
    const int gid = blockIdx.x * blockDim.x + threadIdx.x;
    if (gid >= N) return;

    const float INV2PI = 0.15915494309189533577f;
    const float TWO_PI = 6.28318530717958647692f;
    const float NEXPC  = -0.72134752044448170368f; // -0.5*log2(e)

    const float t     = t_ptr[0];
    const float psi   = psi_a[gid];
    const float theta = theta_a[gid];
    const float vp    = varphi_a[gid] * INV2PI;   // varphi in revolutions

    // cubic Hermite q via precomputed per-interval coeffs: 1 load + 3 fma
    float q;
    {
        const float u = psi * (float)(NPSI - 1);
        int i = (int)floorf(u);
        i = min(max(i, 0), NPSI - 2);
        const float s = u - (float)i;
        const v4f cq = *(const v4f*)(tb + 256 + 4 * i);
        q = fmaf(s, fmaf(s, fmaf(s, cq.w, cq.z), cq.y), cq.x);
    }
    const float q2pi = q * TWO_PI;
    const float tt   = t * INV2PI;                // t in revolutions

    v2f phi = (v2f)0.f, apar = (v2f)0.f;

    #pragma unroll 2
    for (int mp = 0; mp < NMP; ++mp) {
        // contiguous uniform table block -> scalar loads into SGPRs
        const v2f* T = (const v2f*)tb + mp * 30;
        const v2f psi0ps = T[0], invps = T[1], invas = T[2];
        const v2f nf = T[3], th0 = T[4], om = T[5];

        const v2f x  = VFMA((v2f)psi, invps, -psi0ps);
        const v2f x2 = x * x;
        const v2f x4 = 4.f * x2;

        // folded GH poly: p = a0 + c1 x + c3(4x^2) + (c2+c4 x) y + (4c5) y^2
        v2f pa[4], pb[4], pf4[4];
        #pragma unroll
        for (int comp = 0; comp < 4; ++comp) {
            const v2f* B = T + 6 + comp * 6;
            pa[comp]  = VFMA(B[2], x4, VFMA(B[1], x, B[0]));
            pb[comp]  = VFMA(B[4], x, B[3]);
            pf4[comp] = B[5];
        }

        const v2f dth  = (v2f)theta - th0;
        const v2f qdth = q * dth;
        const v2f y0   = qdth * invas;            // y at k=0
        const v2f dy   = q2pi * invas;
        const v2f dphr = nf * q;                  // phase step / 2pi
        const v2f p0r  = VFMA(nf, qdth * INV2PI,
                              VFMA(om, (v2f)tt, -nf * vp));

        // seed trig (revolutions) + rotation recurrence over k
        v2f cp, sp, cd, sd;
        cp.x = COS_REV(p0r.x);  cp.y = COS_REV(p0r.y);
        sp.x = SIN_REV(p0r.x);  sp.y = SIN_REV(p0r.y);
        cd.x = COS_REV(dphr.x); cd.y = COS_REV(dphr.y);
        sd.x = SIN_REV(dphr.x); sd.y = SIN_REV(dphr.y);

        // pass 1: batch the 8 independent exps so the trans pipe pipelines
        v2f gv[KK];
        {
            v2f yk = y0;
            #pragma unroll
            for (int k = 0; k < KK; ++k) {
                const v2f t2 = VFMA(yk, yk, x2);  // x^2+y^2
                const v2f ta = t2 * NEXPC;
                gv[k].x = EXP2F(ta.x);
                gv[k].y = EXP2F(ta.y);
                yk = yk + dy;
            }
        }

        // pass 2: polynomials + rotation + accumulate (y^2 direct, no t2v)
        v2f y = y0;
        #pragma unroll
        for (int k = 0; k < KK; ++k) {
            const v2f y2 = y * y;
            const v2f gc = gv[k] * cp;
            const v2f gs = gv[k] * sp;
            const v2f p0 = VFMA(pf4[0], y2, VFMA(pb[0], y, pa[0]));
            const v2f p1 = VFMA(pf4[1], y2, VFMA(pb[1], y, pa[1]));
            const v2f p2 = VFMA(pf4[2], y2, VFMA(pb[2], y, pa[2]));
            const v2f p3 = VFMA(pf4[3], y2, VFMA(pb[3], y, pa[3]));
            phi  = VFMA(p0, gc, phi);
            phi  = VFMA(-p1, gs, phi);
            apar = VFMA(p2, gc, apar);
            apar = VFMA(-p3, gs, apar);
            if (k < KK - 1) {
                const v2f ncp = VFMA(cp, cd, -(sp * sd));
                const v2f nsp = VFMA(sp, cd,  cp * sd);
                cp = ncp; sp = nsp;
                y = y + dy;
            }
        }
    }

    // horizontal reduce over the (even-m, odd-m) lane split
    out[gid]     = phi.x + phi.y;
    out[N + gid] = apar.x + apar.y;
}

extern "C" void kernel_launch(void* const* d_in, const int* in_sizes, int n_in,
                              void* d_out, int out_size, void* d_ws, size_t ws_size,
                              hipStream_t stream) {
    // 0:t 1:psi 2:theta 3:varphi 4:q_vals 5:aoff_vals 6:theta0 7:omega
    // 8:psi0 9:psi_scale 10:alpha_scale 11:gh_coefs 12:n
    const float* t       = (const float*)d_in[0];
    const float* psi     = (const float*)d_in[1];
    const float* theta   = (const float*)d_in[2];
    const float* varphi  = (const float*)d_in[3];
    const float* q_vals  = (const float*)d_in[4];
    const float* theta0  = (const float*)d_in[6];
    const float* omega   = (const float*)d_in[7];
    const float* psi0    = (const float*)d_in[8];
    const float* psc     = (const float*)d_in[9];
    const float* asc     = (const float*)d_in[10];
    const float* gh      = (const float*)d_in[11];
    const int*   n_arr   = (const int*)d_in[12];

    const int N = in_sizes[1];
    float* out = (float*)d_out;
    float* tb  = (float*)d_ws;   // workspace (poison-filled by harness, fully
                                 // rewritten by prep_kernel every launch)

    prep_kernel<<<1, 256, 0, stream>>>(q_vals, theta0, omega, psi0, psc, asc,
                                       gh, n_arr, tb);

    const int block = 256;
    const int grid  = (N + block - 1) / block;
    eik_kernel<<<grid, block, 0, stream>>>(t, psi, theta, varphi,
                                           tb, out, N);
}